// Round 1
// baseline (366.964 us; speedup 1.0000x reference)
//
#include <hip/hip_runtime.h>
#include <math.h>

#define BIGV 10000.0f

constexpr int B = 32, S = 4096, D = 512;
constexpr int C = 16;          // chunks per batch
constexpr int L = S / C;       // 256 rows per chunk
constexpr int T = 16;          // rows staged per LDS tile (32 KB)
constexpr int NT = L / T;      // tiles per chunk
constexpr int BC = B * C;      // total partial records

// ---------------- kernel 1: per-chunk partials (single pass over x) --------
__global__ __launch_bounds__(512, 4)
void pool_partial(const float* __restrict__ x, const int* __restrict__ mask,
                  const float* __restrict__ w, float* __restrict__ ws) {
  __shared__ float xt[T][D];     // 32 KB tile
  __shared__ float w_s[D];
  __shared__ float sc[T];        // masked scores
  __shared__ float pv[T];        // exp(score - m_new)
  __shared__ int   mk[T];

  const int tid = threadIdx.x;           // == d column, 0..511
  const int blk = blockIdx.x;
  const int b = blk / C, c = blk % C;
  const int s0 = c * L;

  w_s[tid] = w[tid];

  float m = -INFINITY, l = 0.f, cnt = 0.f;
  float o = 0.f, sm = 0.f, mx = -BIGV, mn = BIGV;

  const float4* gsrc = (const float4*)(x + ((size_t)b * S + s0) * D);
  const int* gm = mask + (size_t)b * S + s0;

  const int wave = tid >> 6, lane = tid & 63;

  for (int t = 0; t < NT; ++t) {
    __syncthreads();                      // protect xt from previous tile use
    // ---- stage 16 contiguous rows (32 KB) global -> LDS, float4 ----
    const float4* src = gsrc + (size_t)t * (T * D / 4);
    float4* dst = (float4*)&xt[0][0];
    #pragma unroll
    for (int i = 0; i < (T * D / 4) / 512; ++i)   // 4 float4 per thread
      dst[tid + i * 512] = src[tid + i * 512];
    if (tid < T) mk[tid] = gm[t * T + tid];
    __syncthreads();

    // ---- scores: 8 waves x 2 rows, 8 elems/lane + shuffle reduce ----
    #pragma unroll
    for (int rr = 0; rr < T / 8; ++rr) {
      const int r = wave * (T / 8) + rr;
      float dacc = 0.f;
      #pragma unroll
      for (int k = 0; k < D / 64; ++k)
        dacc = fmaf(xt[r][lane + 64 * k], w_s[lane + 64 * k], dacc);
      #pragma unroll
      for (int off = 32; off; off >>= 1)
        dacc += __shfl_xor(dacc, off, 64);
      if (lane == 0) sc[r] = mk[r] ? dacc : -BIGV;
    }
    __syncthreads();

    // ---- online-softmax tile update (uniform scalar math per thread) ----
    float Mt = -INFINITY;
    #pragma unroll
    for (int r = 0; r < T; ++r) Mt = fmaxf(Mt, sc[r]);   // broadcast reads
    const float m_new = fmaxf(m, Mt);
    const float alpha = __expf(m - m_new);               // exp(-inf)=0 first tile
    o *= alpha; l *= alpha;
    m = m_new;
    if (tid < T) pv[tid] = __expf(sc[tid] - m_new);
    __syncthreads();

    // ---- accumulate pools; thread owns column d=tid (stride-1 LDS) ----
    #pragma unroll
    for (int r = 0; r < T; ++r) {
      const float p    = pv[r];          // broadcast
      const int   mb   = mk[r];          // broadcast
      const float mskf = (float)mb;
      const float xv   = xt[r][tid];     // stride-1, conflict-free
      o  = fmaf(p, xv, o);
      l += p;
      sm = fmaf(mskf, xv, sm);
      mx = fmaxf(mx, mb ? xv : -BIGV);
      mn = fminf(mn, mb ? xv :  BIGV);
      cnt += mskf;
    }
  }

  // ---- write partial record ----
  const size_t idx = (size_t)(b * C + c);
  ws[idx * D + tid]                          = o;
  ws[(size_t)BC * D + idx * D + tid]         = sm;
  ws[2 * (size_t)BC * D + idx * D + tid]     = mx;
  ws[3 * (size_t)BC * D + idx * D + tid]     = mn;
  if (tid == 0) {
    float* scal = ws + 4 * (size_t)BC * D;
    scal[idx]          = m;
    scal[BC + idx]     = l;
    scal[2 * BC + idx] = cnt;
  }
}

// ---------------- kernel 2: merge C partials per batch ---------------------
__global__ __launch_bounds__(512)
void pool_merge(const float* __restrict__ ws, float* __restrict__ out) {
  const int b = blockIdx.x, tid = threadIdx.x;
  const float* scal = ws + 4 * (size_t)BC * D;

  float m_f = -INFINITY;
  #pragma unroll
  for (int c = 0; c < C; ++c) m_f = fmaxf(m_f, scal[b * C + c]);

  float Lsum = 0.f, CNT = 0.f;
  float o = 0.f, sm = 0.f, mx = -BIGV, mn = BIGV;
  #pragma unroll
  for (int c = 0; c < C; ++c) {
    const size_t idx = (size_t)(b * C + c);
    const float a = __expf(scal[idx] - m_f);
    Lsum += scal[BC + idx] * a;
    CNT  += scal[2 * BC + idx];
    o  = fmaf(ws[idx * D + tid], a, o);
    sm += ws[(size_t)BC * D + idx * D + tid];
    mx  = fmaxf(mx, ws[2 * (size_t)BC * D + idx * D + tid]);
    mn  = fminf(mn, ws[3 * (size_t)BC * D + idx * D + tid]);
  }
  float* ob = out + (size_t)b * 4 * D;
  ob[tid]         = sm / (CNT + 1e-6f);
  ob[D + tid]     = mx;
  ob[2 * D + tid] = mn;
  ob[3 * D + tid] = o / Lsum;
}

extern "C" void kernel_launch(void* const* d_in, const int* in_sizes, int n_in,
                              void* d_out, int out_size, void* d_ws, size_t ws_size,
                              hipStream_t stream) {
  const float* x    = (const float*)d_in[0];
  const int*   mask = (const int*)d_in[1];
  const float* w    = (const float*)d_in[2];
  float* out = (float*)d_out;
  float* ws  = (float*)d_ws;

  pool_partial<<<dim3(B * C), dim3(512), 0, stream>>>(x, mask, w, ws);
  pool_merge<<<dim3(B), dim3(512), 0, stream>>>(ws, out);
}